// Round 1
// baseline (755.446 us; speedup 1.0000x reference)
//
#include <hip/hip_runtime.h>
#include <hip/hip_bf16.h>
#include <math.h>

// Problem constants (fixed by setup_inputs)
#define BB 4
#define NN 16384
#define SS 4096
#define D1 128
#define D2 256
#define C1 256   // mlp[0]
#define C2 128   // mlp[1]
#define MTOT (BB*NN)   // 65536

// ---------------------------------------------------------------------------
// 3-NN search. One block = 256 query points of one batch. xyz2[b] staged in
// LDS (48KB) + precomputed ||p||^2 (16KB). Distance formula replicates the
// reference EXACTLY in fp32 (no FMA contraction, same association order) so
// near-tie neighbor selection matches the numpy reference.
// Outputs: idx (global row b*S+s) and normalized weights, 3 per point.
// ---------------------------------------------------------------------------
__global__ __launch_bounds__(256) void knn3_kernel(
    const float* __restrict__ xyz1, const float* __restrict__ xyz2,
    int* __restrict__ idx_out, float* __restrict__ w_out)
{
#pragma clang fp contract(off)
    __shared__ float sx[SS * 3];
    __shared__ float spp[SS];

    const int blocksPerB = NN / 256;          // 64
    const int b = blockIdx.x / blocksPerB;
    const int chunk = blockIdx.x % blocksPerB;

    const float* x2 = xyz2 + (size_t)b * SS * 3;
    for (int i = threadIdx.x; i < SS * 3; i += 256) sx[i] = x2[i];
    __syncthreads();
    for (int s = threadIdx.x; s < SS; s += 256) {
        float px = sx[s*3+0], py = sx[s*3+1], pz = sx[s*3+2];
        spp[s] = (px*px + py*py) + pz*pz;
    }
    __syncthreads();

    const int n = chunk * 256 + threadIdx.x;
    const size_t m = (size_t)b * NN + n;
    const float qx = xyz1[m*3+0], qy = xyz1[m*3+1], qz = xyz1[m*3+2];
    const float qq = (qx*qx + qy*qy) + qz*qz;

    float d0 = 3.4e38f, d1 = 3.4e38f, d2v = 3.4e38f;
    int i0 = 0, i1 = 0, i2 = 0;

#pragma unroll 4
    for (int s = 0; s < SS; ++s) {
        float px = sx[s*3+0], py = sx[s*3+1], pz = sx[s*3+2];
        float cr = (qx*px + qy*py) + qz*pz;
        float d = (qq - 2.0f*cr) + spp[s];
        d = fmaxf(d, 0.0f);
        if (d < d2v) {
            if (d < d1) {
                d2v = d1; i2 = i1;
                if (d < d0) { d1 = d0; i1 = i0; d0 = d; i0 = s; }
                else        { d1 = d;  i1 = s; }
            } else { d2v = d; i2 = s; }
        }
    }

    float r0 = 1.0f / (d0  + 1e-8f);
    float r1 = 1.0f / (d1  + 1e-8f);
    float r2 = 1.0f / (d2v + 1e-8f);
    float z  = (r0 + r1) + r2;
    float inv = 1.0f / z;

    idx_out[m*3+0] = b * SS + i0;
    idx_out[m*3+1] = b * SS + i1;
    idx_out[m*3+2] = b * SS + i2;
    w_out[m*3+0] = r0 * inv;
    w_out[m*3+1] = r1 * inv;
    w_out[m*3+2] = r2 * inv;
}

// ---------------------------------------------------------------------------
// Tiled fp32 GEMM: C[M,N] = op(A[M,K]) @ W[N,K]^T (+ bias)
// op(A) optionally applies per-channel affine + relu (fused BN of prev layer).
// 64x64 tile, TK=16, 256 threads, 4x4 accum per thread.
// ---------------------------------------------------------------------------
template <bool BN_A>
__global__ __launch_bounds__(256) void gemm_kernel(
    const float* __restrict__ A, int lda,
    const float* __restrict__ W, int ldw,
    float* __restrict__ C, int ldc,
    int M, int N, int K,
    const float* __restrict__ bias,
    const float* __restrict__ scaleA,
    const float* __restrict__ shiftA)
{
    const int TM = 64, TN = 64, TK = 16;
    __shared__ float As[TK][TM + 4];
    __shared__ float Ws[TK][TN + 4];

    const int m0 = blockIdx.x * TM;
    const int n0 = blockIdx.y * TN;
    const int tid = threadIdx.x;
    const int tx = tid & 15;        // n dir
    const int ty = tid >> 4;        // m dir
    const int lr = tid >> 2;        // 0..63 load row
    const int lk = (tid & 3) * 4;   // 0,4,8,12 load k

    float acc[4][4] = {};

    for (int k0 = 0; k0 < K; k0 += TK) {
        float4 va = *(const float4*)(A + (size_t)(m0 + lr) * lda + k0 + lk);
        if (BN_A) {
            float4 sc = *(const float4*)(scaleA + k0 + lk);
            float4 sh = *(const float4*)(shiftA + k0 + lk);
            va.x = fmaxf(va.x * sc.x + sh.x, 0.0f);
            va.y = fmaxf(va.y * sc.y + sh.y, 0.0f);
            va.z = fmaxf(va.z * sc.z + sh.z, 0.0f);
            va.w = fmaxf(va.w * sc.w + sh.w, 0.0f);
        }
        float4 vw = *(const float4*)(W + (size_t)(n0 + lr) * ldw + k0 + lk);
        As[lk+0][lr] = va.x; As[lk+1][lr] = va.y; As[lk+2][lr] = va.z; As[lk+3][lr] = va.w;
        Ws[lk+0][lr] = vw.x; Ws[lk+1][lr] = vw.y; Ws[lk+2][lr] = vw.z; Ws[lk+3][lr] = vw.w;
        __syncthreads();

#pragma unroll
        for (int kk = 0; kk < TK; ++kk) {
            float a0 = As[kk][ty*4+0], a1 = As[kk][ty*4+1],
                  a2 = As[kk][ty*4+2], a3 = As[kk][ty*4+3];
            float b0 = Ws[kk][tx*4+0], b1 = Ws[kk][tx*4+1],
                  b2 = Ws[kk][tx*4+2], b3 = Ws[kk][tx*4+3];
            acc[0][0] += a0*b0; acc[0][1] += a0*b1; acc[0][2] += a0*b2; acc[0][3] += a0*b3;
            acc[1][0] += a1*b0; acc[1][1] += a1*b1; acc[1][2] += a1*b2; acc[1][3] += a1*b3;
            acc[2][0] += a2*b0; acc[2][1] += a2*b1; acc[2][2] += a2*b2; acc[2][3] += a2*b3;
            acc[3][0] += a3*b0; acc[3][1] += a3*b1; acc[3][2] += a3*b2; acc[3][3] += a3*b3;
        }
        __syncthreads();
    }

    float4 vb = make_float4(0.f, 0.f, 0.f, 0.f);
    if (bias) vb = *(const float4*)(bias + n0 + tx*4);
#pragma unroll
    for (int i = 0; i < 4; ++i) {
        float4 v;
        v.x = acc[i][0] + vb.x; v.y = acc[i][1] + vb.y;
        v.z = acc[i][2] + vb.z; v.w = acc[i][3] + vb.w;
        *(float4*)(C + (size_t)(m0 + ty*4 + i) * ldc + n0 + tx*4) = v;
    }
}

// ---------------------------------------------------------------------------
// y1[m, :] += sum_k w_k * P2[idx_k, :]   (interp contribution, post-GEMM)
// ---------------------------------------------------------------------------
__global__ __launch_bounds__(256) void interp_add_kernel(
    float* __restrict__ y1, const float* __restrict__ P2,
    const int* __restrict__ idx, const float* __restrict__ w)
{
    const int m = blockIdx.x;
    const int o = threadIdx.x;
    const int i0 = idx[m*3+0], i1 = idx[m*3+1], i2 = idx[m*3+2];
    const float w0 = w[m*3+0], w1 = w[m*3+1], w2 = w[m*3+2];
    float v = y1[(size_t)m*C1 + o];
    v += w0 * P2[(size_t)i0*C1 + o];
    v += w1 * P2[(size_t)i1*C1 + o];
    v += w2 * P2[(size_t)i2*C1 + o];
    y1[(size_t)m*C1 + o] = v;
}

// ---------------------------------------------------------------------------
// Per-channel sum / sumsq over rows (for batch-norm stats). C divides 256.
// ---------------------------------------------------------------------------
__global__ __launch_bounds__(256) void stats_kernel(
    const float* __restrict__ X, int M, int C,
    float* __restrict__ sum, float* __restrict__ sumsq)
{
    const int c = threadIdx.x & (C - 1);
    const int rsub = threadIdx.x / C;
    const int step = 256 / C;
    const int rowsPerBlock = M / gridDim.x;
    const int r0 = blockIdx.x * rowsPerBlock;
    float s = 0.f, s2 = 0.f;
    for (int r = r0 + rsub; r < r0 + rowsPerBlock; r += step) {
        float v = X[(size_t)r * C + c];
        s += v; s2 += v * v;
    }
    atomicAdd(&sum[c], s);
    atomicAdd(&sumsq[c], s2);
}

__global__ void finalize_kernel(
    const float* __restrict__ sum, const float* __restrict__ sumsq,
    const float* __restrict__ g, const float* __restrict__ beta,
    int M, int C, float* __restrict__ scale, float* __restrict__ shift)
{
    int c = threadIdx.x;
    if (c >= C) return;
    float invM = 1.0f / (float)M;
    float mean = sum[c] * invM;
    float var = fmaxf(sumsq[c] * invM - mean * mean, 0.0f);
    float rstd = 1.0f / sqrtf(var + 1e-5f);
    float sc = g[c] * rstd;
    scale[c] = sc;
    shift[c] = beta[c] - mean * sc;
}

__global__ __launch_bounds__(256) void bnrelu_kernel(
    float* __restrict__ X, int total, int C,
    const float* __restrict__ scale, const float* __restrict__ shift)
{
    int i = blockIdx.x * 256 + threadIdx.x;
    if (i >= total) return;
    int c = i & (C - 1);
    X[i] = fmaxf(X[i] * scale[c] + shift[c], 0.0f);
}

// ---------------------------------------------------------------------------
extern "C" void kernel_launch(void* const* d_in, const int* in_sizes, int n_in,
                              void* d_out, int out_size, void* d_ws, size_t ws_size,
                              hipStream_t stream) {
    const float* xyz1    = (const float*)d_in[0];
    const float* xyz2    = (const float*)d_in[1];
    const float* points1 = (const float*)d_in[2];
    const float* points2 = (const float*)d_in[3];
    const float* W1      = (const float*)d_in[4];
    const float* b1      = (const float*)d_in[5];
    const float* g1      = (const float*)d_in[6];
    const float* beta1   = (const float*)d_in[7];
    const float* W2      = (const float*)d_in[8];
    const float* b2      = (const float*)d_in[9];
    const float* g2      = (const float*)d_in[10];
    const float* beta2   = (const float*)d_in[11];
    float* out = (float*)d_out;

    // ws layout (floats)
    char* ws = (char*)d_ws;
    int*   idx = (int*)ws;                                 // MTOT*3 ints
    float* w   = (float*)(ws + (size_t)MTOT*3*4);          // MTOT*3 floats
    float* P2  = (float*)(ws + (size_t)MTOT*6*4);          // B*S*C1
    float* y1  = P2 + (size_t)BB*SS*C1;                    // MTOT*C1
    float* stats = y1 + (size_t)MTOT*C1;
    float* sum1 = stats;            // 256
    float* sq1  = stats + 256;      // 256
    float* sum2 = stats + 512;      // 128
    float* sq2  = stats + 640;      // 128
    float* scale1 = stats + 768;    // 256
    float* shift1 = stats + 1024;   // 256
    float* scale2 = stats + 1280;   // 128
    float* shift2 = stats + 1408;   // 128

    hipMemsetAsync(stats, 0, 768 * sizeof(float), stream);

    // 1) 3-NN + weights
    knn3_kernel<<<BB * (NN/256), 256, 0, stream>>>(xyz1, xyz2, idx, w);

    // 2) P2 = points2 @ W1[:,128:]^T   [B*S, 256]
    gemm_kernel<false><<<dim3((BB*SS)/64, C1/64), 256, 0, stream>>>(
        points2, D2, W1 + D1, D1 + D2, P2, C1, BB*SS, C1, D2,
        nullptr, nullptr, nullptr);

    // 3) y1 = points1 @ W1[:,:128]^T + b1   [M, 256]
    gemm_kernel<false><<<dim3(MTOT/64, C1/64), 256, 0, stream>>>(
        points1, D1, W1, D1 + D2, y1, C1, MTOT, C1, D1,
        b1, nullptr, nullptr);

    // 4) y1 += interp (weighted gather of P2 rows)
    interp_add_kernel<<<MTOT, 256, 0, stream>>>(y1, P2, idx, w);

    // 5) BN1 stats -> scale1/shift1
    stats_kernel<<<512, 256, 0, stream>>>(y1, MTOT, C1, sum1, sq1);
    finalize_kernel<<<1, 256, 0, stream>>>(sum1, sq1, g1, beta1, MTOT, C1, scale1, shift1);

    // 6) y2 = relu(bn1(y1)) @ W2^T + b2 -> d_out (pre-activation)
    gemm_kernel<true><<<dim3(MTOT/64, C2/64), 256, 0, stream>>>(
        y1, C1, W2, C1, out, C2, MTOT, C2, C1,
        b2, scale1, shift1);

    // 7) BN2 stats -> scale2/shift2; apply in place
    stats_kernel<<<512, 256, 0, stream>>>(out, MTOT, C2, sum2, sq2);
    finalize_kernel<<<1, 128, 0, stream>>>(sum2, sq2, g2, beta2, MTOT, C2, scale2, shift2);
    bnrelu_kernel<<<(MTOT*C2)/256, 256, 0, stream>>>(out, MTOT*C2, C2, scale2, shift2);
}